// Round 7
// baseline (289.718 us; speedup 1.0000x reference)
//
#include <hip/hip_runtime.h>
#include <hip/hip_bf16.h>
#include <hip/hip_fp16.h>
#include <math.h>

// ---------------------------------------------------------------------------
typedef __bf16 bf16_t;
typedef __bf16 bf16x8 __attribute__((ext_vector_type(8)));
typedef __bf16 bf16x2 __attribute__((ext_vector_type(2)));
typedef float  f32x4  __attribute__((ext_vector_type(4)));

#define D_MODEL 512
#define NHEAD   8
#define HD      64
#define D_FF    2048
#define TOKENS  8192   // 4 * 2048
#define SEQ     2048
#define BATCH   4

// async global->LDS, 16B per lane; LDS dest = wave-uniform base + lane*16
__device__ __forceinline__ void gload16(const bf16_t* g, bf16_t* l)
{
    __builtin_amdgcn_global_load_lds(
        (const __attribute__((address_space(1))) void*)g,
        (__attribute__((address_space(3))) void*)l,
        16, 0, 0);
}

__device__ __forceinline__ void cvt4(const float* s, bf16_t* d)
{
    float4 v = *(const float4*)s;
    alignas(8) bf16_t t[4] = {(bf16_t)v.x, (bf16_t)v.y, (bf16_t)v.z, (bf16_t)v.w};
    *(uint2*)d = *(const uint2*)t;
}

// raw barrier: NO implicit s_waitcnt vmcnt(0) drain (unlike __syncthreads()).
__device__ __forceinline__ void barrier_raw() { asm volatile("s_barrier" ::: "memory"); }
__device__ __forceinline__ void sched_fence() { __builtin_amdgcn_sched_barrier(0); }

// ---------------------------------------------------------------------------
// src + all weight conversions + bias concat + zero-bias fill in ONE kernel.
// ---------------------------------------------------------------------------
__global__ void cvt_weights(const float* __restrict__ src,
                            const float* __restrict__ Wq, const float* __restrict__ Wk,
                            const float* __restrict__ Wv, const float* __restrict__ Wo,
                            const float* __restrict__ W1, const float* __restrict__ W2,
                            const float* __restrict__ bq, const float* __restrict__ bk,
                            const float* __restrict__ bv,
                            bf16_t* __restrict__ Xb,
                            bf16_t* __restrict__ Wqkvb, bf16_t* __restrict__ Wob,
                            bf16_t* __restrict__ W1b, bf16_t* __restrict__ W2b,
                            float* __restrict__ bqkv, float* __restrict__ zbias)
{
    int i = blockIdx.x * 256 + threadIdx.x;   // one thread = 4 elements
    if (i < 1048576) { cvt4(src + (size_t)i * 4, Xb + (size_t)i * 4); return; }
    i -= 1048576;
    if (i < 65536)        cvt4(Wq + (size_t)i * 4,            Wqkvb + (size_t)i * 4);
    else if (i < 131072)  cvt4(Wk + (size_t)(i - 65536) * 4,  Wqkvb + (size_t)i * 4);
    else if (i < 196608)  cvt4(Wv + (size_t)(i - 131072) * 4, Wqkvb + (size_t)i * 4);
    else if (i < 262144)  cvt4(Wo + (size_t)(i - 196608) * 4, Wob + (size_t)(i - 196608) * 4);
    else if (i < 524288)  cvt4(W1 + (size_t)(i - 262144) * 4, W1b + (size_t)(i - 262144) * 4);
    else if (i < 786432)  cvt4(W2 + (size_t)(i - 524288) * 4, W2b + (size_t)(i - 524288) * 4);
    else if (i < 786816) {
        int j = i - 786432;   // 0..383 -> 1536 bias floats
        const float* s = (j < 128) ? bq + j * 4 : (j < 256) ? bk + (j - 128) * 4
                                                            : bv + (j - 256) * 4;
        *(float4*)(bqkv + (j & 127) * 4 + (j >> 7) * 512) = *(const float4*)s;
    } else if (i < 786944) {
        int j = i - 786816;   // 0..127 -> 512 zero floats
        *(float4*)(zbias + j * 4) = make_float4(0.f, 0.f, 0.f, 0.f);
    }
}

// ---------------------------------------------------------------------------
// gemm256: 256x256 tile, 512 threads (8 waves, 2M x 4N; per-wave 128x64 out).
// BK=64, double-buffered 128 KB LDS, counted-vmcnt raw-barrier pipeline.
// sched_barrier(0) fences pin the phase structure (R4/R6: fixes co-compile
// codegen wobble on the 1-block/CU knife edge; R6 confirmed recovery).
// EPI: 0 = bias->bf16 ; 1 = bias+GELU->bf16
// Requires: M%256==0, N%256==0, K%64==0, K>=128, nwg%8==0.
// ---------------------------------------------------------------------------
template <int EPI>
__global__ __launch_bounds__(512, 2)
void gemm256(const bf16_t* __restrict__ A, const bf16_t* __restrict__ B,
             const float* __restrict__ bias, bf16_t* __restrict__ C,
             int M, int N, int K)
{
    __shared__ bf16_t sA[2][256][64];   // 64 KB
    __shared__ bf16_t sB[2][256][64];   // 64 KB
    bf16_t* sAf = &sA[0][0][0];
    bf16_t* sBf = &sB[0][0][0];

    const int tid  = threadIdx.x;
    const int wave = tid >> 6;
    const int lane = tid & 63;
    const int g    = lane >> 4;
    const int c16  = lane & 15;
    const int wm   = (wave >> 2) * 128;   // wave row offset in tile
    const int wn   = (wave & 3) * 64;     // wave col offset in tile

    // bijective XCD-chunked swizzle (grids here are %8==0)
    const int nwg  = gridDim.x * gridDim.y;
    const int flat = blockIdx.y * gridDim.x + blockIdx.x;
    const int swz  = (flat & 7) * (nwg >> 3) + (flat >> 3);
    const int m0   = (swz / gridDim.x) * 256;
    const int n0   = (swz % gridDim.x) * 256;

    const f32x4 fz = {0.f, 0.f, 0.f, 0.f};
    f32x4 acc[8][4];
#pragma unroll
    for (int i = 0; i < 8; i++)
#pragma unroll
        for (int j = 0; j < 4; j++) acc[i][j] = fz;

    // DMA staging map: flat 16B-chunk f = issue*512 + tid; row = f>>3,
    // physical chunk p = f&7 receives LOGICAL chunk l = p ^ (row&7).
    const bf16_t* gA[4]; const bf16_t* gB[4]; int fa[4];
#pragma unroll
    for (int i = 0; i < 4; i++) {
        const int f = i * 512 + tid, row = f >> 3, l = (f & 7) ^ (row & 7);
        fa[i] = f;
        gA[i] = A + (size_t)(m0 + row) * K + l * 8;
        gB[i] = B + (size_t)(n0 + row) * K + l * 8;
    }

    auto stage = [&](int ko, int buf) {
        bf16_t* dA = sAf + buf * (256 * 64);
        bf16_t* dB = sBf + buf * (256 * 64);
#pragma unroll
        for (int i = 0; i < 4; i++) gload16(gA[i] + ko, dA + fa[i] * 8);
#pragma unroll
        for (int i = 0; i < 4; i++) gload16(gB[i] + ko, dB + fa[i] * 8);
    };

    // prologue: two stages in flight
    stage(0, 0);
    stage(64, 1);

    const int NS = K >> 6;
    for (int s = 0; s < NS; ++s) {
        const int cur = s & 1;
        // wait for stage s only; stage s+1's 8 loads stay outstanding
        if (s + 1 < NS) asm volatile("s_waitcnt vmcnt(8)" ::: "memory");
        else            asm volatile("s_waitcnt vmcnt(0)" ::: "memory");
        barrier_raw();
        sched_fence();   // nothing from the compute phase moves above this

#pragma unroll
        for (int ks = 0; ks < 2; ++ks) {
            // fragment row&7 == c16&7 -> physical chunk = logical ^ (c16&7)
            const int ck = ((ks * 4 + g) ^ (c16 & 7)) * 8;
            bf16x8 af[8], bfr[4];
#pragma unroll
            for (int i = 0; i < 8; i++)
                af[i] = *(const bf16x8*)&sA[cur][wm + i * 16 + c16][ck];
#pragma unroll
            for (int j = 0; j < 4; j++)
                bfr[j] = *(const bf16x8*)&sB[cur][wn + j * 16 + c16][ck];
#pragma unroll
            for (int mi = 0; mi < 8; mi++)
#pragma unroll
                for (int ni = 0; ni < 4; ni++)
                    acc[mi][ni] = __builtin_amdgcn_mfma_f32_16x16x32_bf16(
                        af[mi], bfr[ni], acc[mi][ni], 0, 0, 0);
        }

        sched_fence();   // compute phase fully emitted before the barrier
        barrier_raw();   // everyone done reading buf[cur]
        if (s + 2 < NS) stage((s + 2) << 6, cur);
        sched_fence();   // prefetch issue stays in its own phase
    }

    // epilogue
    float bcol[4];
#pragma unroll
    for (int ni = 0; ni < 4; ni++) bcol[ni] = bias[n0 + wn + ni * 16 + c16];
#pragma unroll
    for (int mi = 0; mi < 8; mi++) {
#pragma unroll
        for (int ni = 0; ni < 4; ni++) {
            const int col = n0 + wn + ni * 16 + c16;
#pragma unroll
            for (int r = 0; r < 4; r++) {
                const int row = m0 + wm + mi * 16 + g * 4 + r;
                float v = acc[mi][ni][r] + bcol[ni];
                if (EPI == 1) v = 0.5f * v * (1.f + erff(v * 0.70710678118654752f));
                C[(size_t)row * N + col] = (bf16_t)v;
            }
        }
    }
}

// ---------------------------------------------------------------------------
// GEMM (Wo / W2 split-K partial paths): BM x 128 tile, 256 thr, BK=64,
// double-buffered, counted-vmcnt raw-barrier pipeline (R1 config, measured
// good inside the 273.6us wall).
// SPLIT2: gridDim.z==2, each z-half does K/2, writes fp16 partials at
//         Cout + z*M*N; z==1 uses biasz (zeros) so bias applies once.
// EPI: 2 = bias->fp16 partial
// ---------------------------------------------------------------------------
template <int BM, int EPI, bool SPLIT2>
__global__ __launch_bounds__(256)
void gemm_bt(const bf16_t* __restrict__ A, const bf16_t* __restrict__ B,
             const float* __restrict__ bias, const float* __restrict__ biasz,
             void* __restrict__ Cout, int M, int N, int K)
{
    constexpr int MI = BM / 32;     // m-fragments per wave
    constexpr int NA = BM / 32;     // A DMA issues per stage
    __shared__ bf16_t sA[2][BM][64];   // 16/32 KB
    __shared__ bf16_t sB[2][128][64];  // 32 KB
    bf16_t* sAf = &sA[0][0][0];
    bf16_t* sBf = &sB[0][0][0];

    const int tid  = threadIdx.x;
    const int wave = tid >> 6;
    const int lane = tid & 63;
    const int g    = lane >> 4;
    const int c16  = lane & 15;
    const int wm   = (wave >> 1) * (BM / 2);
    const int wn   = (wave & 1) * 64;
    const int m0   = blockIdx.y * BM;
    const int n0   = blockIdx.x * 128;

    const int zz    = SPLIT2 ? blockIdx.z : 0;
    const int Keff  = SPLIT2 ? (K >> 1) : K;
    const int kbase = zz * Keff;
    const float* bptr = (SPLIT2 && zz) ? biasz : bias;

    const f32x4 fz = {0.f, 0.f, 0.f, 0.f};
    f32x4 acc[MI][4];
#pragma unroll
    for (int i = 0; i < MI; i++)
#pragma unroll
        for (int j = 0; j < 4; j++) acc[i][j] = fz;

    const bf16_t* gA[NA]; int fa[NA];
#pragma unroll
    for (int i = 0; i < NA; i++) {
        const int f = i * 256 + tid, row = f >> 3, l = (f & 7) ^ (row & 7);
        fa[i] = f;
        gA[i] = A + (size_t)(m0 + row) * K + kbase + l * 8;
    }
    const bf16_t* gB[4]; int fb[4];
#pragma unroll
    for (int i = 0; i < 4; i++) {
        const int f = i * 256 + tid, row = f >> 3, l = (f & 7) ^ (row & 7);
        fb[i] = f;
        gB[i] = B + (size_t)(n0 + row) * K + kbase + l * 8;
    }

    auto stage = [&](int ko, int buf) {
        bf16_t* dA = sAf + buf * (BM * 64);
        bf16_t* dB = sBf + buf * 8192;
#pragma unroll
        for (int i = 0; i < NA; i++) gload16(gA[i] + ko, dA + fa[i] * 8);
#pragma unroll
        for (int i = 0; i < 4; i++)  gload16(gB[i] + ko, dB + fb[i] * 8);
    };

    // prologue: stages 0 and 1 both in flight
    stage(0, 0);
    stage(64, 1);

    const int NS = Keff >> 6;
    for (int s = 0; s < NS; ++s) {
        const int cur = s & 1;
        if (s + 1 < NS) {
            if constexpr (NA == 2) asm volatile("s_waitcnt vmcnt(6)" ::: "memory");
            else                   asm volatile("s_waitcnt vmcnt(8)" ::: "memory");
        } else {
            asm volatile("s_waitcnt vmcnt(0)" ::: "memory");
        }
        barrier_raw();
        sched_fence();

#pragma unroll
        for (int sub = 0; sub < 2; ++sub) {
            const int ck = (((sub * 4 + g) ^ (c16 & 7))) * 8;
            bf16x8 af[MI], bfr[4];
#pragma unroll
            for (int i = 0; i < MI; i++)
                af[i] = *(const bf16x8*)&sA[cur][wm + i * 16 + c16][ck];
#pragma unroll
            for (int j = 0; j < 4; j++)
                bfr[j] = *(const bf16x8*)&sB[cur][wn + j * 16 + c16][ck];
#pragma unroll
            for (int mi = 0; mi < MI; mi++)
#pragma unroll
                for (int ni = 0; ni < 4; ni++)
                    acc[mi][ni] = __builtin_amdgcn_mfma_f32_16x16x32_bf16(
                        af[mi], bfr[ni], acc[mi][ni], 0, 0, 0);
        }

        sched_fence();
        barrier_raw();                       // everyone done reading buf[cur]
        if (s + 2 < NS) stage((s + 2) << 6, cur);
        sched_fence();
    }

    __half* outh = (__half*)Cout + (size_t)zz * M * N;
#pragma unroll
    for (int mi = 0; mi < MI; mi++) {
#pragma unroll
        for (int ni = 0; ni < 4; ni++) {
            const int col = n0 + wn + ni * 16 + c16;
            const float bv = bptr[col];
#pragma unroll
            for (int r = 0; r < 4; r++) {
                const int row = m0 + wm + mi * 16 + g * 4 + r;
                float v = acc[mi][ni][r] + bv;
                if (EPI == 1) v = 0.5f * v * (1.f + erff(v * 0.70710678118654752f));
                if (EPI == 2)
                    outh[(size_t)row * N + col] = (__half)v;
                else
                    ((bf16_t*)Cout)[(size_t)row * N + col] = (bf16_t)v;
            }
        }
    }
}

// ---------------------------------------------------------------------------
// transpose V out of QKV into Vt[bh][64][2048]. Position p within each 64-t
// tile holds token sigma(p) = (p>>5)*32 + ((p>>2)&1)*16 + ((p>>3)&3)*4 + (p&3).
// ---------------------------------------------------------------------------
__global__ __launch_bounds__(256)
void transpose_v(const bf16_t* __restrict__ qkv, bf16_t* __restrict__ vt)
{
    __shared__ bf16_t st[64][72];
    const int t0 = blockIdx.x * 64;
    const int bh = blockIdx.y;
    const int b = bh >> 3, h = bh & 7;
    const int tid = threadIdx.x;

    for (int c = tid; c < 512; c += 256) {
        int r = c >> 3, cj = (c & 7) * 8;
        const bf16_t* src = qkv + ((size_t)(b * SEQ + t0 + r)) * 1536 + 1024 + h * 64 + cj;
        *(int4*)&st[r][cj] = *(const int4*)src;
    }
    __syncthreads();
    for (int c = tid; c < 512; c += 256) {
        int d = c >> 3, pj = (c & 7) * 8;
        alignas(16) bf16_t tmp[8];
#pragma unroll
        for (int j = 0; j < 8; j++) {
            int p = pj + j;
            int t = ((p >> 5) << 5) + (((p >> 2) & 1) << 4) + (((p >> 3) & 3) << 2) + (p & 3);
            tmp[j] = st[t][d];
        }
        *(int4*)(vt + ((size_t)(bh * 64 + d)) * SEQ + t0 + pj) = *(const int4*)tmp;
    }
}

// ---------------------------------------------------------------------------
// Flash attention v13: v12's 512-thr/8-wave/16-q layout, v10 intra-iter order
// (qk -> softmax -> pv, same tile, setprio on both MFMA clusters), K and V
// TRIPLE-buffered -> 48 KB LDS -> 3 blocks/CU -> 24 waves/CU (6/SIMD).
// R6 showed 2 blocks/CU leaves ~18us of in-block barrier lockstep unhidden;
// the T15 retime (worth ~2us) forced quad-V/64KB which capped occupancy.
// Safety (%3 buffers, ONE barrier/iter): during iter t all waves read only
// buf t%3; in-flight DMA targets (t+1)%3; stage(t+2) targets (t+2)%3 -- both
// != t%3. vmcnt(2) steady (one 2-load stage outstanding). grid (16,32).
// ---------------------------------------------------------------------------
__global__ __launch_bounds__(512)
__attribute__((amdgpu_waves_per_eu(6)))
void flash_attn(const bf16_t* __restrict__ qkv, const bf16_t* __restrict__ vt,
                bf16_t* __restrict__ ctx)
{
    __shared__ bf16_t sK[3][64][64];    // 24 KB (triple buffer)
    __shared__ bf16_t sVt[3][64][64];   // 24 KB

    const int bh = blockIdx.y;
    const int b = bh >> 3, h = bh & 7;
    const int q0 = blockIdx.x * 128;
    const int tid = threadIdx.x;
    const int wave = tid >> 6, lane = tid & 63;
    const int g = lane >> 4, c16 = lane & 15;

    const float qscale = 0.125f * 1.4426950408889634f;   // 1/sqrt(64) * log2(e)
    bf16x8 aq[2];   // [ks] B-operand fragments of Q (wave's 16 q-rows)
#pragma unroll
    for (int ks = 0; ks < 2; ks++) {
        bf16x8 v = *(const bf16x8*)(qkv +
            ((size_t)(b * SEQ + q0 + wave * 16 + c16)) * 1536 +
            h * 64 + ks * 32 + g * 8);
#pragma unroll
        for (int j = 0; j < 8; j++) v[j] = (bf16_t)((float)v[j] * qscale);
        aq[ks] = v;
    }

    const f32x4 fz = {0.f, 0.f, 0.f, 0.f};
    f32x4 acc_oT[4];   // [dt] : O^T, col=q', row=d_local
#pragma unroll
    for (int dt = 0; dt < 4; dt++) acc_oT[dt] = fz;
    float l_acc = 0.f;

    // 512 threads cover a full 64x64 bf16 tile (8 KB) in ONE gload16 issue.
    const int f0 = tid, r0 = f0 >> 3, l0 = (f0 & 7) ^ (r0 & 7);
    const bf16_t* gK0 = qkv + ((size_t)(b * SEQ + r0)) * 1536 + 512 + h * 64 + l0 * 8;
    const bf16_t* gV0 = vt + ((size_t)(bh * 64 + r0)) * SEQ + l0 * 8;
    bf16_t* lK = &sK[0][0][0];
    bf16_t* lV = &sVt[0][0][0];

    // stage KV tile t into buffer t%3 (2 DMA loads per thread-call)
    auto stageKV = [&](int t) {
        const int bo = (t % 3) * 4096;
        const size_t kv = (size_t)t * 64;
        gload16(gK0 + kv * 1536, lK + bo + f0 * 8);
        gload16(gV0 + kv,        lV + bo + f0 * 8);
    };

    // S^T of tile (buffer cur) into accs
    f32x4 accs[4];
    auto qk_mfma = [&](int cur) {
#pragma unroll
        for (int tt = 0; tt < 4; tt++) accs[tt] = fz;
#pragma unroll
        for (int ks = 0; ks < 2; ks++) {
            const int pc = ((ks * 4 + g) ^ (c16 & 7)) * 8;
#pragma unroll
            for (int tt = 0; tt < 4; tt++) {
                bf16x8 ak = *(const bf16x8*)&sK[cur][tt * 16 + c16][pc];
                accs[tt] = __builtin_amdgcn_mfma_f32_16x16x32_bf16(ak, aq[ks], accs[tt], 0, 0, 0);
            }
        }
    };

    bf16x8 pb[2];   // [kv] packed P fragments of the CURRENT tile
    auto pv_mfma = [&](int cur) {
#pragma unroll
        for (int kv = 0; kv < 2; kv++) {
            const int pc = ((kv * 4 + g) ^ (c16 & 7)) * 8;
#pragma unroll
            for (int dt = 0; dt < 4; dt++) {
                bf16x8 av = *(const bf16x8*)&sVt[cur][dt * 16 + c16][pc];
                acc_oT[dt] = __builtin_amdgcn_mfma_f32_16x16x32_bf16(av, pb[kv], acc_oT[dt], 0, 0, 0);
            }
        }
    };

    // softmax: accs -> exp2 in regs, row-sum into l_acc, pack into pb
    auto softmax_pack = [&]() {
#pragma unroll
        for (int tt = 0; tt < 4; tt++) {
            float s = 0.f;
#pragma unroll
            for (int r = 0; r < 4; r++) {
                float p = __builtin_amdgcn_exp2f(accs[tt][r]);
                accs[tt][r] = p;
                s += p;
            }
            l_acc += s;
        }
#pragma unroll
        for (int kv = 0; kv < 2; kv++)
#pragma unroll
            for (int j = 0; j < 8; j++)
                pb[kv][j] = (bf16_t)accs[kv * 2 + (j >> 2)][j & 3];
    };

    // prologue: two tiles in flight
    stageKV(0);
    stageKV(1);

    for (int it = 0; it < 32; ++it) {
        const int cur = it % 3;
        // wait for tile it; tile it+1's 2 loads stay outstanding
        if (it < 31) asm volatile("s_waitcnt vmcnt(2)" ::: "memory");
        else         asm volatile("s_waitcnt vmcnt(0)" ::: "memory");
        barrier_raw();

        __builtin_amdgcn_s_setprio(1);
        qk_mfma(cur);
        __builtin_amdgcn_s_setprio(0);
        softmax_pack();
        __builtin_amdgcn_s_setprio(1);
        pv_mfma(cur);
        __builtin_amdgcn_s_setprio(0);

        if (it + 2 < 32) stageKV(it + 2);
    }

    // epilogue: lane (q'=c16, g) holds O[token][d] for d = dt*16 + g*4 + r.
    {
        float l = l_acc;
        l += __shfl_xor(l, 16);
        l += __shfl_xor(l, 32);
        const float inv = 1.0f / l;
        const int token = q0 + wave * 16 + c16;
        bf16_t* dst = ctx + ((size_t)(b * SEQ + token)) * 512 + h * 64 + g * 4;
#pragma unroll
        for (int dt = 0; dt < 4; dt++) {
            alignas(8) bf16_t o4[4];
#pragma unroll
            for (int r = 0; r < 4; r++) o4[r] = (bf16_t)(acc_oT[dt][r] * inv);
            *(uint2*)(dst + dt * 16) = *(const uint2*)o4;
        }
    }
}

// ---------------------------------------------------------------------------
// out = LayerNorm(a + b + c) * gamma + beta ; a fp32, b/c fp16 partials.
// ---------------------------------------------------------------------------
__global__ __launch_bounds__(256)
void add_ln3(const float* __restrict__ a, const __half* __restrict__ b,
             const __half* __restrict__ c,
             const float* __restrict__ gamma, const float* __restrict__ beta,
             float* __restrict__ outf, bf16_t* __restrict__ outb)
{
    const int row  = blockIdx.x * 4 + (threadIdx.x >> 6);
    const int lane = threadIdx.x & 63;
    const size_t base = (size_t)row * 512 + lane * 8;

    int4 braw = *(const int4*)(b + base);   // 8 halves
    int4 craw = *(const int4*)(c + base);
    const __half* bh = (const __half*)&braw;
    const __half* ch = (const __half*)&craw;

    float v[8];
#pragma unroll
    for (int hh = 0; hh < 2; hh++) {
        float4 av = *(const float4*)(a + base + hh * 4);
        v[hh * 4 + 0] = av.x + (float)bh[hh * 4 + 0] + (float)ch[hh * 4 + 0];
        v[hh * 4 + 1] = av.y + (float)bh[hh * 4 + 1] + (float)ch[hh * 4 + 1];
        v[hh * 4 + 2] = av.z + (float)bh[hh * 4 + 2] + (float)ch[hh * 4 + 2];
        v[hh * 4 + 3] = av.w + (float)bh[hh * 4 + 3] + (float)ch[hh * 4 + 3];
    }

    float s = 0.f;
#pragma unroll
    for (int i = 0; i < 8; i++) s += v[i];
#pragma unroll
    for (int off = 32; off > 0; off >>= 1) s += __shfl_xor(s, off);
    const float mu = s * (1.f / 512.f);

    float q = 0.f;
#pragma unroll
    for (int i = 0; i < 8; i++) { float d = v[i] - mu; q += d * d; }
#pragma unroll
    for (int off = 32; off > 0; off >>= 1) q += __shfl_xor(q, off);
    const float rstd = rsqrtf(q * (1.f / 512.f) + 1e-5f);

    float4 g0 = *(const float4*)(gamma + lane * 8);
    float4 g1 = *(const float4*)(gamma + lane * 8 + 4);
    float4 e0 = *(const float4*)(beta + lane * 8);
    float4 e1 = *(const float4*)(beta + lane * 8 + 4);
    const float gg[8] = {g0.x, g0.y, g0.z, g0.w, g1.x, g1.y, g1.z, g1.w};
    const float ee[8] = {e0.x, e0.y, e0.z, e0.w, e1.x, e1.y, e1.z, e1.w};

    float o[8];
#pragma unroll
    for (int i = 0; i < 8; i++) o[i] = (v[i] - mu) * rstd * gg[i] + ee[i];

    *(float4*)(outf + base)     = make_float4(o[0], o[1], o[2], o[3]);
    *(float4*)(outf + base + 4) = make_float4(o[4], o[5], o[6], o[7]);
    if (outb) {
        alignas(16) bf16_t ob[8];
#pragma unroll
        for (int i = 0; i < 8; i++) ob[i] = (bf16_t)o[i];
        *(int4*)(outb + base) = *(const int4*)ob;
    }
}

// ---------------------------------------------------------------------------
extern "C" void kernel_launch(void* const* d_in, const int* in_sizes, int n_in,
                              void* d_out, int out_size, void* d_ws, size_t ws_size,
                              hipStream_t stream)
{
    const float* src = (const float*)d_in[0];
    const float* Wq  = (const float*)d_in[1];  const float* bq  = (const float*)d_in[2];
    const float* Wk  = (const float*)d_in[3];  const float* bk  = (const float*)d_in[4];
    const float* Wv  = (const float*)d_in[5];  const float* bv  = (const float*)d_in[6];
    const float* Wo  = (const float*)d_in[7];  const float* bo  = (const float*)d_in[8];
    const float* W1  = (const float*)d_in[9];  const float* b1  = (const float*)d_in[10];
    const float* W2  = (const float*)d_in[11]; const float* b2  = (const float*)d_in[12];
    const float* g1  = (const float*)d_in[13]; const float* be1 = (const float*)d_in[14];
    const float* g2  = (const float*)d_in[15]; const float* be2 = (const float*)d_in[16];
    float* out = (float*)d_out;

    char* ws = (char*)d_ws;
    size_t off = 0;
    auto alloc = [&](size_t bytes) -> void* {
        void* p = ws + off;
        off = (off + bytes + 255) & ~(size_t)255;
        return p;
    };

    bf16_t* Xb    = (bf16_t*)alloc((size_t)TOKENS * 512 * 2);
    bf16_t* Wqkvb = (bf16_t*)alloc((size_t)1536 * 512 * 2);
    bf16_t* Wob   = (bf16_t*)alloc((size_t)512 * 512 * 2);
    bf16_t* W1b   = (bf16_t*)alloc((size_t)2048 * 512 * 2);
    bf16_t* W2b   = (bf16_t*)alloc((size_t)512 * 2048 * 2);
    float*  bqkv  = (float*)alloc(1536 * 4);
    float*  zbias = (float*)alloc(512 * 4);
    bf16_t* QKV   = (bf16_t*)alloc((size_t)TOKENS * 1536 * 2);  // contiguous with Vt
    bf16_t* Vt    = (bf16_t*)alloc((size_t)32 * 64 * SEQ * 2);
    bf16_t* CTX   = (bf16_t*)alloc((size_t)TOKENS * 512 * 2);
    __half* ATTa  = (__half*)alloc((size_t)TOKENS * 512 * 2);   // contiguous with ATTb
    __half* ATTb  = (__half*)alloc((size_t)TOKENS * 512 * 2);
    float*  X1    = (float*)alloc((size_t)TOKENS * 512 * 4);
    bf16_t* X1b   = (bf16_t*)alloc((size_t)TOKENS * 512 * 2);

    bf16_t* H    = QKV;    // alias: QKV+Vt (33.55 MB exactly) dead after flash
    __half* FFNa = ATTa;   // alias: ATTa/ATTb dead after ln1 (contiguous pair)
    __half* FFNb = ATTb;

    cvt_weights<<<7170, 256, 0, stream>>>(src, Wq, Wk, Wv, Wo, W1, W2, bq, bk, bv,
                                          Xb, Wqkvb, Wob, W1b, W2b, bqkv, zbias);

    // fused QKV projection: 256x256 tiles, grid (6,32) = 192 blocks (%8==0)
    gemm256<0><<<dim3(6, 32), 512, 0, stream>>>(
        Xb, Wqkvb, bqkv, QKV, TOKENS, 1536, 512);

    transpose_v<<<dim3(32, 32), 256, 0, stream>>>(QKV, Vt);
    flash_attn<<<dim3(16, 32), 512, 0, stream>>>(QKV, Vt, CTX);

    // Wo projection, split-K=2 -> fp16 partials ATTa/ATTb
    gemm_bt<64, 2, true><<<dim3(4, 128, 2), 256, 0, stream>>>(
        CTX, Wob, bo, zbias, ATTa, TOKENS, 512, 512);

    add_ln3<<<2048, 256, 0, stream>>>(src, ATTa, ATTb, g1, be1, X1, X1b);

    // FFN1 + GELU: 256x256 tiles, grid (8,32) = 256 blocks = 1/CU
    gemm256<1><<<dim3(8, 32), 512, 0, stream>>>(
        X1b, W1b, b1, H, TOKENS, 2048, 512);

    // W2, split-K=2 -> fp16 partials FFNa/FFNb
    gemm_bt<64, 2, true><<<dim3(4, 128, 2), 256, 0, stream>>>(
        H, W2b, b2, zbias, FFNa, TOKENS, 512, 2048);

    add_ln3<<<2048, 256, 0, stream>>>(X1, FFNa, FFNb, g2, be2, out, nullptr);
}

// Round 8
// 265.676 us; speedup vs baseline: 1.0905x; 1.0905x over previous
//
#include <hip/hip_runtime.h>
#include <hip/hip_bf16.h>
#include <hip/hip_fp16.h>
#include <math.h>

// ---------------------------------------------------------------------------
typedef __bf16 bf16_t;
typedef __bf16 bf16x8 __attribute__((ext_vector_type(8)));
typedef __bf16 bf16x2 __attribute__((ext_vector_type(2)));
typedef float  f32x4  __attribute__((ext_vector_type(4)));

#define D_MODEL 512
#define NHEAD   8
#define HD      64
#define D_FF    2048
#define TOKENS  8192   // 4 * 2048
#define SEQ     2048
#define BATCH   4

// async global->LDS, 16B per lane; LDS dest = wave-uniform base + lane*16
__device__ __forceinline__ void gload16(const bf16_t* g, bf16_t* l)
{
    __builtin_amdgcn_global_load_lds(
        (const __attribute__((address_space(1))) void*)g,
        (__attribute__((address_space(3))) void*)l,
        16, 0, 0);
}

__device__ __forceinline__ void cvt4(const float* s, bf16_t* d)
{
    float4 v = *(const float4*)s;
    alignas(8) bf16_t t[4] = {(bf16_t)v.x, (bf16_t)v.y, (bf16_t)v.z, (bf16_t)v.w};
    *(uint2*)d = *(const uint2*)t;
}

// raw barrier: NO implicit s_waitcnt vmcnt(0) drain (unlike __syncthreads()).
__device__ __forceinline__ void barrier_raw() { asm volatile("s_barrier" ::: "memory"); }
__device__ __forceinline__ void sched_fence() { __builtin_amdgcn_sched_barrier(0); }

// Exact-GELU via Abramowitz-Stegun 7.1.26 erf approx (|eps|<1.5e-7, far
// below bf16 ulp). PURE FMA + exp2 -- no libdevice call. R7 DIAGNOSIS: the
// erff() libcall was the only code unique to the slow-mode-afflicted EPI==1
// instantiation; a non-inlined call caps the kernel's VGPR budget (observed
// VGPR_Count=92 vs a 128-reg accumulator) and tanks the K-loop schedule.
__device__ __forceinline__ float gelu_f(float x)
{
    const float y = fabsf(x) * 0.70710678118654752f;
    const float t = 1.0f / fmaf(0.3275911f, y, 1.0f);
    float p = fmaf(1.061405429f, t, -1.453152027f);
    p = fmaf(p, t, 1.421413741f);
    p = fmaf(p, t, -0.284496736f);
    p = fmaf(p, t, 0.254829592f);
    p *= t;
    const float e = __builtin_amdgcn_exp2f(-y * y * 1.4426950408889634f);
    float erfv = 1.0f - p * e;
    erfv = (x < 0.f) ? -erfv : erfv;
    return 0.5f * x * (1.0f + erfv);
}

// ---------------------------------------------------------------------------
// src + all weight conversions + bias concat + zero-bias fill in ONE kernel.
// ---------------------------------------------------------------------------
__global__ void cvt_weights(const float* __restrict__ src,
                            const float* __restrict__ Wq, const float* __restrict__ Wk,
                            const float* __restrict__ Wv, const float* __restrict__ Wo,
                            const float* __restrict__ W1, const float* __restrict__ W2,
                            const float* __restrict__ bq, const float* __restrict__ bk,
                            const float* __restrict__ bv,
                            bf16_t* __restrict__ Xb,
                            bf16_t* __restrict__ Wqkvb, bf16_t* __restrict__ Wob,
                            bf16_t* __restrict__ W1b, bf16_t* __restrict__ W2b,
                            float* __restrict__ bqkv, float* __restrict__ zbias)
{
    int i = blockIdx.x * 256 + threadIdx.x;   // one thread = 4 elements
    if (i < 1048576) { cvt4(src + (size_t)i * 4, Xb + (size_t)i * 4); return; }
    i -= 1048576;
    if (i < 65536)        cvt4(Wq + (size_t)i * 4,            Wqkvb + (size_t)i * 4);
    else if (i < 131072)  cvt4(Wk + (size_t)(i - 65536) * 4,  Wqkvb + (size_t)i * 4);
    else if (i < 196608)  cvt4(Wv + (size_t)(i - 131072) * 4, Wqkvb + (size_t)i * 4);
    else if (i < 262144)  cvt4(Wo + (size_t)(i - 196608) * 4, Wob + (size_t)(i - 196608) * 4);
    else if (i < 524288)  cvt4(W1 + (size_t)(i - 262144) * 4, W1b + (size_t)(i - 262144) * 4);
    else if (i < 786432)  cvt4(W2 + (size_t)(i - 524288) * 4, W2b + (size_t)(i - 524288) * 4);
    else if (i < 786816) {
        int j = i - 786432;   // 0..383 -> 1536 bias floats
        const float* s = (j < 128) ? bq + j * 4 : (j < 256) ? bk + (j - 128) * 4
                                                            : bv + (j - 256) * 4;
        *(float4*)(bqkv + (j & 127) * 4 + (j >> 7) * 512) = *(const float4*)s;
    } else if (i < 786944) {
        int j = i - 786816;   // 0..127 -> 512 zero floats
        *(float4*)(zbias + j * 4) = make_float4(0.f, 0.f, 0.f, 0.f);
    }
}

// ---------------------------------------------------------------------------
// gemm256: 256x256 tile, 512 threads (8 waves, 2M x 4N; per-wave 128x64 out).
// BK=64, double-buffered 128 KB LDS, counted-vmcnt raw-barrier pipeline,
// sched_barrier(0) phase pins. EPI: 0 = bias->bf16 ; 1 = bias+GELU->bf16.
// Requires: M%256==0, N%256==0, K%64==0, K>=128, nwg%8==0.
// ---------------------------------------------------------------------------
template <int EPI>
__global__ __launch_bounds__(512, 2)
void gemm256(const bf16_t* __restrict__ A, const bf16_t* __restrict__ B,
             const float* __restrict__ bias, bf16_t* __restrict__ C,
             int M, int N, int K)
{
    __shared__ bf16_t sA[2][256][64];   // 64 KB
    __shared__ bf16_t sB[2][256][64];   // 64 KB
    bf16_t* sAf = &sA[0][0][0];
    bf16_t* sBf = &sB[0][0][0];

    const int tid  = threadIdx.x;
    const int wave = tid >> 6;
    const int lane = tid & 63;
    const int g    = lane >> 4;
    const int c16  = lane & 15;
    const int wm   = (wave >> 2) * 128;   // wave row offset in tile
    const int wn   = (wave & 3) * 64;     // wave col offset in tile

    // bijective XCD-chunked swizzle (grids here are %8==0)
    const int nwg  = gridDim.x * gridDim.y;
    const int flat = blockIdx.y * gridDim.x + blockIdx.x;
    const int swz  = (flat & 7) * (nwg >> 3) + (flat >> 3);
    const int m0   = (swz / gridDim.x) * 256;
    const int n0   = (swz % gridDim.x) * 256;

    const f32x4 fz = {0.f, 0.f, 0.f, 0.f};
    f32x4 acc[8][4];
#pragma unroll
    for (int i = 0; i < 8; i++)
#pragma unroll
        for (int j = 0; j < 4; j++) acc[i][j] = fz;

    // DMA staging map: flat 16B-chunk f = issue*512 + tid; row = f>>3,
    // physical chunk p = f&7 receives LOGICAL chunk l = p ^ (row&7).
    const bf16_t* gA[4]; const bf16_t* gB[4]; int fa[4];
#pragma unroll
    for (int i = 0; i < 4; i++) {
        const int f = i * 512 + tid, row = f >> 3, l = (f & 7) ^ (row & 7);
        fa[i] = f;
        gA[i] = A + (size_t)(m0 + row) * K + l * 8;
        gB[i] = B + (size_t)(n0 + row) * K + l * 8;
    }

    auto stage = [&](int ko, int buf) {
        bf16_t* dA = sAf + buf * (256 * 64);
        bf16_t* dB = sBf + buf * (256 * 64);
#pragma unroll
        for (int i = 0; i < 4; i++) gload16(gA[i] + ko, dA + fa[i] * 8);
#pragma unroll
        for (int i = 0; i < 4; i++) gload16(gB[i] + ko, dB + fa[i] * 8);
    };

    // prologue: two stages in flight
    stage(0, 0);
    stage(64, 1);

    const int NS = K >> 6;
    for (int s = 0; s < NS; ++s) {
        const int cur = s & 1;
        // wait for stage s only; stage s+1's 8 loads stay outstanding
        if (s + 1 < NS) asm volatile("s_waitcnt vmcnt(8)" ::: "memory");
        else            asm volatile("s_waitcnt vmcnt(0)" ::: "memory");
        barrier_raw();
        sched_fence();   // nothing from the compute phase moves above this

#pragma unroll
        for (int ks = 0; ks < 2; ++ks) {
            // fragment row&7 == c16&7 -> physical chunk = logical ^ (c16&7)
            const int ck = ((ks * 4 + g) ^ (c16 & 7)) * 8;
            bf16x8 af[8], bfr[4];
#pragma unroll
            for (int i = 0; i < 8; i++)
                af[i] = *(const bf16x8*)&sA[cur][wm + i * 16 + c16][ck];
#pragma unroll
            for (int j = 0; j < 4; j++)
                bfr[j] = *(const bf16x8*)&sB[cur][wn + j * 16 + c16][ck];
#pragma unroll
            for (int mi = 0; mi < 8; mi++)
#pragma unroll
                for (int ni = 0; ni < 4; ni++)
                    acc[mi][ni] = __builtin_amdgcn_mfma_f32_16x16x32_bf16(
                        af[mi], bfr[ni], acc[mi][ni], 0, 0, 0);
        }

        sched_fence();   // compute phase fully emitted before the barrier
        barrier_raw();   // everyone done reading buf[cur]
        if (s + 2 < NS) stage((s + 2) << 6, cur);
        sched_fence();   // prefetch issue stays in its own phase
    }

    // epilogue
    float bcol[4];
#pragma unroll
    for (int ni = 0; ni < 4; ni++) bcol[ni] = bias[n0 + wn + ni * 16 + c16];
#pragma unroll
    for (int mi = 0; mi < 8; mi++) {
#pragma unroll
        for (int ni = 0; ni < 4; ni++) {
            const int col = n0 + wn + ni * 16 + c16;
#pragma unroll
            for (int r = 0; r < 4; r++) {
                const int row = m0 + wm + mi * 16 + g * 4 + r;
                float v = acc[mi][ni][r] + bcol[ni];
                if (EPI == 1) v = gelu_f(v);
                C[(size_t)row * N + col] = (bf16_t)v;
            }
        }
    }
}

// ---------------------------------------------------------------------------
// GEMM (Wo / W2 split-K partial paths): BM x 128 tile, 256 thr, BK=64,
// double-buffered, counted-vmcnt raw-barrier pipeline.
// SPLIT2: gridDim.z==2, each z-half does K/2, writes fp16 partials at
//         Cout + z*M*N; z==1 uses biasz (zeros) so bias applies once.
// EPI: 2 = bias->fp16 partial
// ---------------------------------------------------------------------------
template <int BM, int EPI, bool SPLIT2>
__global__ __launch_bounds__(256)
void gemm_bt(const bf16_t* __restrict__ A, const bf16_t* __restrict__ B,
             const float* __restrict__ bias, const float* __restrict__ biasz,
             void* __restrict__ Cout, int M, int N, int K)
{
    constexpr int MI = BM / 32;     // m-fragments per wave
    constexpr int NA = BM / 32;     // A DMA issues per stage
    __shared__ bf16_t sA[2][BM][64];   // 16/32 KB
    __shared__ bf16_t sB[2][128][64];  // 32 KB
    bf16_t* sAf = &sA[0][0][0];
    bf16_t* sBf = &sB[0][0][0];

    const int tid  = threadIdx.x;
    const int wave = tid >> 6;
    const int lane = tid & 63;
    const int g    = lane >> 4;
    const int c16  = lane & 15;
    const int wm   = (wave >> 1) * (BM / 2);
    const int wn   = (wave & 1) * 64;
    const int m0   = blockIdx.y * BM;
    const int n0   = blockIdx.x * 128;

    const int zz    = SPLIT2 ? blockIdx.z : 0;
    const int Keff  = SPLIT2 ? (K >> 1) : K;
    const int kbase = zz * Keff;
    const float* bptr = (SPLIT2 && zz) ? biasz : bias;

    const f32x4 fz = {0.f, 0.f, 0.f, 0.f};
    f32x4 acc[MI][4];
#pragma unroll
    for (int i = 0; i < MI; i++)
#pragma unroll
        for (int j = 0; j < 4; j++) acc[i][j] = fz;

    const bf16_t* gA[NA]; int fa[NA];
#pragma unroll
    for (int i = 0; i < NA; i++) {
        const int f = i * 256 + tid, row = f >> 3, l = (f & 7) ^ (row & 7);
        fa[i] = f;
        gA[i] = A + (size_t)(m0 + row) * K + kbase + l * 8;
    }
    const bf16_t* gB[4]; int fb[4];
#pragma unroll
    for (int i = 0; i < 4; i++) {
        const int f = i * 256 + tid, row = f >> 3, l = (f & 7) ^ (row & 7);
        fb[i] = f;
        gB[i] = B + (size_t)(n0 + row) * K + kbase + l * 8;
    }

    auto stage = [&](int ko, int buf) {
        bf16_t* dA = sAf + buf * (BM * 64);
        bf16_t* dB = sBf + buf * 8192;
#pragma unroll
        for (int i = 0; i < NA; i++) gload16(gA[i] + ko, dA + fa[i] * 8);
#pragma unroll
        for (int i = 0; i < 4; i++)  gload16(gB[i] + ko, dB + fb[i] * 8);
    };

    // prologue: stages 0 and 1 both in flight
    stage(0, 0);
    stage(64, 1);

    const int NS = Keff >> 6;
    for (int s = 0; s < NS; ++s) {
        const int cur = s & 1;
        if (s + 1 < NS) {
            if constexpr (NA == 2) asm volatile("s_waitcnt vmcnt(6)" ::: "memory");
            else                   asm volatile("s_waitcnt vmcnt(8)" ::: "memory");
        } else {
            asm volatile("s_waitcnt vmcnt(0)" ::: "memory");
        }
        barrier_raw();
        sched_fence();

#pragma unroll
        for (int sub = 0; sub < 2; ++sub) {
            const int ck = (((sub * 4 + g) ^ (c16 & 7))) * 8;
            bf16x8 af[MI], bfr[4];
#pragma unroll
            for (int i = 0; i < MI; i++)
                af[i] = *(const bf16x8*)&sA[cur][wm + i * 16 + c16][ck];
#pragma unroll
            for (int j = 0; j < 4; j++)
                bfr[j] = *(const bf16x8*)&sB[cur][wn + j * 16 + c16][ck];
#pragma unroll
            for (int mi = 0; mi < MI; mi++)
#pragma unroll
                for (int ni = 0; ni < 4; ni++)
                    acc[mi][ni] = __builtin_amdgcn_mfma_f32_16x16x32_bf16(
                        af[mi], bfr[ni], acc[mi][ni], 0, 0, 0);
        }

        sched_fence();
        barrier_raw();                       // everyone done reading buf[cur]
        if (s + 2 < NS) stage((s + 2) << 6, cur);
        sched_fence();
    }

    __half* outh = (__half*)Cout + (size_t)zz * M * N;
#pragma unroll
    for (int mi = 0; mi < MI; mi++) {
#pragma unroll
        for (int ni = 0; ni < 4; ni++) {
            const int col = n0 + wn + ni * 16 + c16;
            const float bv = bptr[col];
#pragma unroll
            for (int r = 0; r < 4; r++) {
                const int row = m0 + wm + mi * 16 + g * 4 + r;
                float v = acc[mi][ni][r] + bv;
                if (EPI == 1) v = gelu_f(v);
                if (EPI == 2)
                    outh[(size_t)row * N + col] = (__half)v;
                else
                    ((bf16_t*)Cout)[(size_t)row * N + col] = (bf16_t)v;
            }
        }
    }
}

// ---------------------------------------------------------------------------
// transpose V out of QKV into Vt[bh][64][2048]. Position p within each 64-t
// tile holds token sigma(p) = (p>>5)*32 + ((p>>2)&1)*16 + ((p>>3)&3)*4 + (p&3).
// ---------------------------------------------------------------------------
__global__ __launch_bounds__(256)
void transpose_v(const bf16_t* __restrict__ qkv, bf16_t* __restrict__ vt)
{
    __shared__ bf16_t st[64][72];
    const int t0 = blockIdx.x * 64;
    const int bh = blockIdx.y;
    const int b = bh >> 3, h = bh & 7;
    const int tid = threadIdx.x;

    for (int c = tid; c < 512; c += 256) {
        int r = c >> 3, cj = (c & 7) * 8;
        const bf16_t* src = qkv + ((size_t)(b * SEQ + t0 + r)) * 1536 + 1024 + h * 64 + cj;
        *(int4*)&st[r][cj] = *(const int4*)src;
    }
    __syncthreads();
    for (int c = tid; c < 512; c += 256) {
        int d = c >> 3, pj = (c & 7) * 8;
        alignas(16) bf16_t tmp[8];
#pragma unroll
        for (int j = 0; j < 8; j++) {
            int p = pj + j;
            int t = ((p >> 5) << 5) + (((p >> 2) & 1) << 4) + (((p >> 3) & 3) << 2) + (p & 3);
            tmp[j] = st[t][d];
        }
        *(int4*)(vt + ((size_t)(bh * 64 + d)) * SEQ + t0 + pj) = *(const int4*)tmp;
    }
}

// ---------------------------------------------------------------------------
// Flash attention v13 (unchanged from R7): 512 thr / 8 waves / 16 q-rows,
// qk -> softmax -> pv same-tile order, triple-buffered K,V (48 KB LDS ->
// 3 blocks/CU, 6 waves/SIMD), counted-vmcnt(2), ONE raw barrier/iter.
// ---------------------------------------------------------------------------
__global__ __launch_bounds__(512)
__attribute__((amdgpu_waves_per_eu(6)))
void flash_attn(const bf16_t* __restrict__ qkv, const bf16_t* __restrict__ vt,
                bf16_t* __restrict__ ctx)
{
    __shared__ bf16_t sK[3][64][64];    // 24 KB (triple buffer)
    __shared__ bf16_t sVt[3][64][64];   // 24 KB

    const int bh = blockIdx.y;
    const int b = bh >> 3, h = bh & 7;
    const int q0 = blockIdx.x * 128;
    const int tid = threadIdx.x;
    const int wave = tid >> 6, lane = tid & 63;
    const int g = lane >> 4, c16 = lane & 15;

    const float qscale = 0.125f * 1.4426950408889634f;   // 1/sqrt(64) * log2(e)
    bf16x8 aq[2];   // [ks] B-operand fragments of Q (wave's 16 q-rows)
#pragma unroll
    for (int ks = 0; ks < 2; ks++) {
        bf16x8 v = *(const bf16x8*)(qkv +
            ((size_t)(b * SEQ + q0 + wave * 16 + c16)) * 1536 +
            h * 64 + ks * 32 + g * 8);
#pragma unroll
        for (int j = 0; j < 8; j++) v[j] = (bf16_t)((float)v[j] * qscale);
        aq[ks] = v;
    }

    const f32x4 fz = {0.f, 0.f, 0.f, 0.f};
    f32x4 acc_oT[4];   // [dt] : O^T, col=q', row=d_local
#pragma unroll
    for (int dt = 0; dt < 4; dt++) acc_oT[dt] = fz;
    float l_acc = 0.f;

    // 512 threads cover a full 64x64 bf16 tile (8 KB) in ONE gload16 issue.
    const int f0 = tid, r0 = f0 >> 3, l0 = (f0 & 7) ^ (r0 & 7);
    const bf16_t* gK0 = qkv + ((size_t)(b * SEQ + r0)) * 1536 + 512 + h * 64 + l0 * 8;
    const bf16_t* gV0 = vt + ((size_t)(bh * 64 + r0)) * SEQ + l0 * 8;
    bf16_t* lK = &sK[0][0][0];
    bf16_t* lV = &sVt[0][0][0];

    // stage KV tile t into buffer t%3 (2 DMA loads per thread-call)
    auto stageKV = [&](int t) {
        const int bo = (t % 3) * 4096;
        const size_t kv = (size_t)t * 64;
        gload16(gK0 + kv * 1536, lK + bo + f0 * 8);
        gload16(gV0 + kv,        lV + bo + f0 * 8);
    };

    // S^T of tile (buffer cur) into accs
    f32x4 accs[4];
    auto qk_mfma = [&](int cur) {
#pragma unroll
        for (int tt = 0; tt < 4; tt++) accs[tt] = fz;
#pragma unroll
        for (int ks = 0; ks < 2; ks++) {
            const int pc = ((ks * 4 + g) ^ (c16 & 7)) * 8;
#pragma unroll
            for (int tt = 0; tt < 4; tt++) {
                bf16x8 ak = *(const bf16x8*)&sK[cur][tt * 16 + c16][pc];
                accs[tt] = __builtin_amdgcn_mfma_f32_16x16x32_bf16(ak, aq[ks], accs[tt], 0, 0, 0);
            }
        }
    };

    bf16x8 pb[2];   // [kv] packed P fragments of the CURRENT tile
    auto pv_mfma = [&](int cur) {
#pragma unroll
        for (int kv = 0; kv < 2; kv++) {
            const int pc = ((kv * 4 + g) ^ (c16 & 7)) * 8;
#pragma unroll
            for (int dt = 0; dt < 4; dt++) {
                bf16x8 av = *(const bf16x8*)&sVt[cur][dt * 16 + c16][pc];
                acc_oT[dt] = __builtin_amdgcn_mfma_f32_16x16x32_bf16(av, pb[kv], acc_oT[dt], 0, 0, 0);
            }
        }
    };

    // softmax: accs -> exp2 in regs, row-sum into l_acc, pack into pb
    auto softmax_pack = [&]() {
#pragma unroll
        for (int tt = 0; tt < 4; tt++) {
            float s = 0.f;
#pragma unroll
            for (int r = 0; r < 4; r++) {
                float p = __builtin_amdgcn_exp2f(accs[tt][r]);
                accs[tt][r] = p;
                s += p;
            }
            l_acc += s;
        }
#pragma unroll
        for (int kv = 0; kv < 2; kv++)
#pragma unroll
            for (int j = 0; j < 8; j++)
                pb[kv][j] = (bf16_t)accs[kv * 2 + (j >> 2)][j & 3];
    };

    // prologue: two tiles in flight
    stageKV(0);
    stageKV(1);

    for (int it = 0; it < 32; ++it) {
        const int cur = it % 3;
        // wait for tile it; tile it+1's 2 loads stay outstanding
        if (it < 31) asm volatile("s_waitcnt vmcnt(2)" ::: "memory");
        else         asm volatile("s_waitcnt vmcnt(0)" ::: "memory");
        barrier_raw();

        __builtin_amdgcn_s_setprio(1);
        qk_mfma(cur);
        __builtin_amdgcn_s_setprio(0);
        softmax_pack();
        __builtin_amdgcn_s_setprio(1);
        pv_mfma(cur);
        __builtin_amdgcn_s_setprio(0);

        if (it + 2 < 32) stageKV(it + 2);
    }

    // epilogue: lane (q'=c16, g) holds O[token][d] for d = dt*16 + g*4 + r.
    {
        float l = l_acc;
        l += __shfl_xor(l, 16);
        l += __shfl_xor(l, 32);
        const float inv = 1.0f / l;
        const int token = q0 + wave * 16 + c16;
        bf16_t* dst = ctx + ((size_t)(b * SEQ + token)) * 512 + h * 64 + g * 4;
#pragma unroll
        for (int dt = 0; dt < 4; dt++) {
            alignas(8) bf16_t o4[4];
#pragma unroll
            for (int r = 0; r < 4; r++) o4[r] = (bf16_t)(acc_oT[dt][r] * inv);
            *(uint2*)(dst + dt * 16) = *(const uint2*)o4;
        }
    }
}

// ---------------------------------------------------------------------------
// out = LayerNorm(a + b + c) * gamma + beta ; a fp32, b/c fp16 partials.
// ---------------------------------------------------------------------------
__global__ __launch_bounds__(256)
void add_ln3(const float* __restrict__ a, const __half* __restrict__ b,
             const __half* __restrict__ c,
             const float* __restrict__ gamma, const float* __restrict__ beta,
             float* __restrict__ outf, bf16_t* __restrict__ outb)
{
    const int row  = blockIdx.x * 4 + (threadIdx.x >> 6);
    const int lane = threadIdx.x & 63;
    const size_t base = (size_t)row * 512 + lane * 8;

    int4 braw = *(const int4*)(b + base);   // 8 halves
    int4 craw = *(const int4*)(c + base);
    const __half* bh = (const __half*)&braw;
    const __half* ch = (const __half*)&craw;

    float v[8];
#pragma unroll
    for (int hh = 0; hh < 2; hh++) {
        float4 av = *(const float4*)(a + base + hh * 4);
        v[hh * 4 + 0] = av.x + (float)bh[hh * 4 + 0] + (float)ch[hh * 4 + 0];
        v[hh * 4 + 1] = av.y + (float)bh[hh * 4 + 1] + (float)ch[hh * 4 + 1];
        v[hh * 4 + 2] = av.z + (float)bh[hh * 4 + 2] + (float)ch[hh * 4 + 2];
        v[hh * 4 + 3] = av.w + (float)bh[hh * 4 + 3] + (float)ch[hh * 4 + 3];
    }

    float s = 0.f;
#pragma unroll
    for (int i = 0; i < 8; i++) s += v[i];
#pragma unroll
    for (int off = 32; off > 0; off >>= 1) s += __shfl_xor(s, off);
    const float mu = s * (1.f / 512.f);

    float q = 0.f;
#pragma unroll
    for (int i = 0; i < 8; i++) { float d = v[i] - mu; q += d * d; }
#pragma unroll
    for (int off = 32; off > 0; off >>= 1) q += __shfl_xor(q, off);
    const float rstd = rsqrtf(q * (1.f / 512.f) + 1e-5f);

    float4 g0 = *(const float4*)(gamma + lane * 8);
    float4 g1 = *(const float4*)(gamma + lane * 8 + 4);
    float4 e0 = *(const float4*)(beta + lane * 8);
    float4 e1 = *(const float4*)(beta + lane * 8 + 4);
    const float gg[8] = {g0.x, g0.y, g0.z, g0.w, g1.x, g1.y, g1.z, g1.w};
    const float ee[8] = {e0.x, e0.y, e0.z, e0.w, e1.x, e1.y, e1.z, e1.w};

    float o[8];
#pragma unroll
    for (int i = 0; i < 8; i++) o[i] = (v[i] - mu) * rstd * gg[i] + ee[i];

    *(float4*)(outf + base)     = make_float4(o[0], o[1], o[2], o[3]);
    *(float4*)(outf + base + 4) = make_float4(o[4], o[5], o[6], o[7]);
    if (outb) {
        alignas(16) bf16_t ob[8];
#pragma unroll
        for (int i = 0; i < 8; i++) ob[i] = (bf16_t)o[i];
        *(int4*)(outb + base) = *(const int4*)ob;
    }
}

// ---------------------------------------------------------------------------
extern "C" void kernel_launch(void* const* d_in, const int* in_sizes, int n_in,
                              void* d_out, int out_size, void* d_ws, size_t ws_size,
                              hipStream_t stream)
{
    const float* src = (const float*)d_in[0];
    const float* Wq  = (const float*)d_in[1];  const float* bq  = (const float*)d_in[2];
    const float* Wk  = (const float*)d_in[3];  const float* bk  = (const float*)d_in[4];
    const float* Wv  = (const float*)d_in[5];  const float* bv  = (const float*)d_in[6];
    const float* Wo  = (const float*)d_in[7];  const float* bo  = (const float*)d_in[8];
    const float* W1  = (const float*)d_in[9];  const float* b1  = (const float*)d_in[10];
    const float* W2  = (const float*)d_in[11]; const float* b2  = (const float*)d_in[12];
    const float* g1  = (const float*)d_in[13]; const float* be1 = (const float*)d_in[14];
    const float* g2  = (const float*)d_in[15]; const float* be2 = (const float*)d_in[16];
    float* out = (float*)d_out;

    char* ws = (char*)d_ws;
    size_t off = 0;
    auto alloc = [&](size_t bytes) -> void* {
        void* p = ws + off;
        off = (off + bytes + 255) & ~(size_t)255;
        return p;
    };

    bf16_t* Xb    = (bf16_t*)alloc((size_t)TOKENS * 512 * 2);
    bf16_t* Wqkvb = (bf16_t*)alloc((size_t)1536 * 512 * 2);
    bf16_t* Wob   = (bf16_t*)alloc((size_t)512 * 512 * 2);
    bf16_t* W1b   = (bf16_t*)alloc((size_t)2048 * 512 * 2);
    bf16_t* W2b   = (bf16_t*)alloc((size_t)512 * 2048 * 2);
    float*  bqkv  = (float*)alloc(1536 * 4);
    float*  zbias = (float*)alloc(512 * 4);
    bf16_t* QKV   = (bf16_t*)alloc((size_t)TOKENS * 1536 * 2);  // contiguous with Vt
    bf16_t* Vt    = (bf16_t*)alloc((size_t)32 * 64 * SEQ * 2);
    bf16_t* CTX   = (bf16_t*)alloc((size_t)TOKENS * 512 * 2);
    __half* ATTa  = (__half*)alloc((size_t)TOKENS * 512 * 2);   // contiguous with ATTb
    __half* ATTb  = (__half*)alloc((size_t)TOKENS * 512 * 2);
    float*  X1    = (float*)alloc((size_t)TOKENS * 512 * 4);
    bf16_t* X1b   = (bf16_t*)alloc((size_t)TOKENS * 512 * 2);

    bf16_t* H    = QKV;    // alias: QKV+Vt (33.55 MB exactly) dead after flash
    __half* FFNa = ATTa;   // alias: ATTa/ATTb dead after ln1 (contiguous pair)
    __half* FFNb = ATTb;

    cvt_weights<<<7170, 256, 0, stream>>>(src, Wq, Wk, Wv, Wo, W1, W2, bq, bk, bv,
                                          Xb, Wqkvb, Wob, W1b, W2b, bqkv, zbias);

    // fused QKV projection: 256x256 tiles, grid (6,32) = 192 blocks (%8==0)
    gemm256<0><<<dim3(6, 32), 512, 0, stream>>>(
        Xb, Wqkvb, bqkv, QKV, TOKENS, 1536, 512);

    transpose_v<<<dim3(32, 32), 256, 0, stream>>>(QKV, Vt);
    flash_attn<<<dim3(16, 32), 512, 0, stream>>>(QKV, Vt, CTX);

    // Wo projection, split-K=2 -> fp16 partials ATTa/ATTb
    gemm_bt<64, 2, true><<<dim3(4, 128, 2), 256, 0, stream>>>(
        CTX, Wob, bo, zbias, ATTa, TOKENS, 512, 512);

    add_ln3<<<2048, 256, 0, stream>>>(src, ATTa, ATTb, g1, be1, X1, X1b);

    // FFN1 + GELU: 256x256 tiles, grid (8,32) = 256 blocks = 1/CU
    gemm256<1><<<dim3(8, 32), 512, 0, stream>>>(
        X1b, W1b, b1, H, TOKENS, 2048, 512);

    // W2, split-K=2 -> fp16 partials FFNa/FFNb
    gemm_bt<64, 2, true><<<dim3(4, 128, 2), 256, 0, stream>>>(
        H, W2b, b2, zbias, FFNa, TOKENS, 512, 2048);

    add_ln3<<<2048, 256, 0, stream>>>(X1, FFNa, FFNb, g2, be2, out, nullptr);
}